// Round 15
// baseline (786.748 us; speedup 1.0000x reference)
//
#include <hip/hip_runtime.h>
#include <hip/hip_bf16.h>
#include <stdint.h>

typedef __attribute__((ext_vector_type(8))) short short8;
typedef __attribute__((ext_vector_type(4))) float f32x4;

#define B_ 32
#define N_ 196
#define D_ 1024
#define V_ 32000
#define NSTEP 99
#define MROWS 3168   // 99*32
#define MPAD  3200
#define SENT  0x7FC07FC07FC07FC0ULL   // 4x bf16 NaN: unreachable as packed h (|h|<1)
#define NITEMS 3250  // 13 g-groups (256 rows) x 250 n-tiles (128 cols)

// workspace layout (bytes)
#define OFF_WT     0ULL          // bf16 [32000][1024]  = 65,536,000
#define OFF_H      65536000ULL   // bf16 [3200][1024]   =  6,553,600  (u64 view: [99][8192] + pad)
#define OFF_FSUM   72089600ULL   // f32  [32][1024]
#define OFF_CTXP   72220672ULL   // f32  [2][32][1024]  partials
#define OFF_GBASEP 72482816ULL   // f32  [4][32][4096]  partials = 2,097,152
#define OFF_CTL    74579968ULL   // u32 ctl[0]=bh0 prog, [1]=bh1 prog, [2]=convT done, [3]=item ctr

#define AS3 __attribute__((address_space(3)))
#define AS1 __attribute__((address_space(1)))
static __device__ __forceinline__ void gload_lds16(const void* g, void* l) {
  __builtin_amdgcn_global_load_lds((const AS1 uint32_t*)g, (AS3 uint32_t*)l, 16, 0, 0);
}
static __device__ __forceinline__ unsigned long long aload(const unsigned long long* p) {
  return __hip_atomic_load(p, __ATOMIC_RELAXED, __HIP_MEMORY_SCOPE_AGENT);
}

// ---------------- fsum (blocks 0..127) + sentinel-fill H (blocks 128..383) ----------------
__global__ void k_fsum(const float* __restrict__ feat, float* __restrict__ fsum,
                       unsigned long long* __restrict__ Hq) {
  if (blockIdx.x >= 128) {
    int gid = (blockIdx.x - 128) * 256 + threadIdx.x;   // 65536 threads
    for (int w = gid; w < NSTEP * 8192; w += 65536) Hq[w] = SENT;
    return;
  }
  int idx = blockIdx.x * 256 + threadIdx.x;           // 32768
  int b = idx >> 10, e = idx & 1023;
  const float* p = feat + (size_t)b * (N_ * D_) + e;
  float s = 0.f;
  #pragma unroll 4
  for (int n = 0; n < N_; ++n) s += fmaxf(p[(size_t)n * D_], 0.f);
  fsum[idx] = s;
}

// ---------------- ctxp[kc] = fsum[:,e-chunk] @ W_fv[e-chunk,:] (+196*b_fv in kc0) ----------------
__global__ void k_ctx(const float* __restrict__ fsum, const float* __restrict__ W_fv,
                      const float* __restrict__ b_fv, float* __restrict__ ctxp) {
  __shared__ float fs[16][512];
  int kc = blockIdx.z;
  int e0 = kc * 512;
  int b0 = blockIdx.y * 16;
  int d = blockIdx.x * 64 + (threadIdx.x & 63);
  int bq = threadIdx.x >> 6;
  for (int i = threadIdx.x; i < 8192; i += 256)
    fs[i >> 9][i & 511] = fsum[(b0 + (i >> 9)) * 1024 + e0 + (i & 511)];
  __syncthreads();
  float bias = (kc == 0) ? 196.f * b_fv[d] : 0.f;
  float acc[4] = {bias, bias, bias, bias};
  for (int e4 = 0; e4 < 128; ++e4) {
    float w0 = W_fv[(size_t)(e0 + 4 * e4 + 0) * 1024 + d];
    float w1 = W_fv[(size_t)(e0 + 4 * e4 + 1) * 1024 + d];
    float w2 = W_fv[(size_t)(e0 + 4 * e4 + 2) * 1024 + d];
    float w3 = W_fv[(size_t)(e0 + 4 * e4 + 3) * 1024 + d];
    #pragma unroll
    for (int r = 0; r < 4; ++r) {
      float4 c = *(const float4*)&fs[bq * 4 + r][e4 * 4];
      acc[r] = fmaf(c.x, w0, fmaf(c.y, w1, fmaf(c.z, w2, fmaf(c.w, w3, acc[r]))));
    }
  }
  #pragma unroll
  for (int r = 0; r < 4; ++r)
    ctxp[kc * 32768 + (size_t)(b0 + bq * 4 + r) * 1024 + d] = acc[r];
}

// ---------------- gbasep[kc] = ctx[:,e-chunk] @ W_ih[e-chunk,:] (+biases in kc0) ----------------
__global__ void k_gbase(const float* __restrict__ ctxp, const float* __restrict__ W_ih,
                        const float* __restrict__ b_ih, const float* __restrict__ b_hh,
                        float* __restrict__ gbasep) {
  __shared__ float cs[16][256];
  int kc = blockIdx.z;
  int e0 = kc * 256;
  int b0 = blockIdx.y * 16;
  int j = blockIdx.x * 256 + threadIdx.x;
  for (int i = threadIdx.x; i < 4096; i += 256) {
    int r = i >> 8, e = i & 255;
    cs[r][e] = ctxp[(size_t)(b0 + r) * 1024 + e0 + e]
             + ctxp[32768 + (size_t)(b0 + r) * 1024 + e0 + e];
  }
  __syncthreads();
  float bias = (kc == 0) ? (b_ih[j] + b_hh[j]) : 0.f;
  float acc[16];
  #pragma unroll
  for (int r = 0; r < 16; ++r) acc[r] = bias;
  for (int e4 = 0; e4 < 64; ++e4) {
    float w0 = W_ih[(size_t)(e0 + 4 * e4 + 0) * 4096 + j];
    float w1 = W_ih[(size_t)(e0 + 4 * e4 + 1) * 4096 + j];
    float w2 = W_ih[(size_t)(e0 + 4 * e4 + 2) * 4096 + j];
    float w3 = W_ih[(size_t)(e0 + 4 * e4 + 3) * 4096 + j];
    #pragma unroll
    for (int r = 0; r < 16; ++r) {
      float4 c = *(const float4*)&cs[r][e4 * 4];
      acc[r] = fmaf(c.x, w0, fmaf(c.y, w1, fmaf(c.z, w2, fmaf(c.w, w3, acc[r]))));
    }
  }
  #pragma unroll
  for (int r = 0; r < 16; ++r)
    gbasep[kc * 131072 + (size_t)(b0 + r) * 4096 + j] = acc[r];
}

// ================= fused persistent kernel: 256 blocks x 512 threads =================
// blocks 0..127 : rec (2-D decomp, 512-thr: poll 8 words/thread) -> GEMM consumer
// blocks 128..255: one-hot + pad-zero + convT (NT) -> GEMM consumer
// GEMM: work-queue of (g: 256 rows, nt: 128 cols) items, gated on rep progress counters;
//       A staged via agent-atomic u64 loads (coherent), B via gload_lds after threadfence.
__global__ __launch_bounds__(512, 2) void k_rec(
    const float* __restrict__ gbasep, const float* __restrict__ W_hh,
    const float* __restrict__ bos, unsigned long long* __restrict__ Hq,
    const float* __restrict__ W_lm, __hip_bfloat16* __restrict__ WT,
    const float* __restrict__ b_lm, float* __restrict__ out,
    uint32_t* __restrict__ ctl) {
  extern __shared__ char lds[];
  const int tid = threadIdx.x;
  const int blk = blockIdx.x;
  const int lane = tid & 63;
  const int wid = tid >> 6;           // 0..7

  if (blk >= 128) {
    // ============ worker: one-hot + pad zero + convT ============
    __hip_bfloat16* t = (__hip_bfloat16*)lds;          // [64][66]
    int wblk = blk - 128;
    for (int idx = wblk * 512 + tid; idx < B_ * V_; idx += 128 * 512)
      __builtin_nontemporal_store(((idx % V_) == 0) ? 1.0f : 0.0f, &out[idx]);
    // zero pad rows 3168..3199 via AGENT atomics (coherent for later atomic A-reads)
    if (wblk < 16)
      __hip_atomic_store(&Hq[(size_t)MROWS * 256 + wblk * 512 + tid], 0ULL,
                         __ATOMIC_RELAXED, __HIP_MEMORY_SCOPE_AGENT);
    int tx = tid & 63, ty = tid >> 6;                  // 8 waves
    int word = tx & 31, nh = tx >> 5;
    for (int tile = wblk; tile < 8000; tile += 128) {
      int k0 = (tile & 15) * 64;
      int n0 = (tile >> 4) * 64;
      __syncthreads();
      #pragma unroll
      for (int i = 0; i < 8; ++i) {
        int r = i * 8 + ty;
        t[r * 66 + tx] = __float2bfloat16(
            __builtin_nontemporal_load(&W_lm[(size_t)(k0 + r) * V_ + n0 + tx]));
      }
      __syncthreads();
      #pragma unroll
      for (int i = 0; i < 4; ++i) {
        int n = i * 16 + ty * 2 + nh;
        uint32_t lo = *(const uint16_t*)&t[2 * word * 66 + n];
        uint32_t hi = *(const uint16_t*)&t[(2 * word + 1) * 66 + n];
        __builtin_nontemporal_store(lo | (hi << 16),
            (uint32_t*)&WT[(size_t)(n0 + n) * 1024 + k0] + word);
      }
    }
    asm volatile("s_waitcnt vmcnt(0)" ::: "memory");
    __threadfence();                                   // release: L2 writeback
    __syncthreads();
    if (tid == 0) atomicAdd(&ctl[2], 1u);
  } else {
    // ============ recurrence (2-D decomp, 512 threads) ============
    __hip_bfloat16* hbuf = (__hip_bfloat16*)lds;             // [16][1024] swizzled (32 KB)
    __hip_bfloat16* wbuf = (__hip_bfloat16*)(lds + 32768);   // [64][1024] (init only, 128 KB)
    float* gex = (float*)(lds + 32768);                      // [16][68] f32, aliases wbuf

    const int bh = blk >> 6;     // batch half 0..1
    const int dg = blk & 63;     // dim group 0..63

    for (int idx = tid; idx < 64 * 1024; idx += 512) {
      int c = idx & 63;
      int k = idx >> 6;
      float w = W_hh[(size_t)k * 4096 + (c >> 4) * 1024 + dg * 16 + (c & 15)];
      wbuf[c * 1024 + ((((k >> 3) ^ (c & 7)) << 3) | (k & 7))] = __float2bfloat16(w);
    }
    for (int idx = tid; idx < 16 * 1024; idx += 512) {
      int row = idx >> 10;
      int k = idx & 1023;
      hbuf[row * 1024 + ((((k >> 3) ^ (row & 7)) << 3) | (k & 7))] = __float2bfloat16(bos[k]);
    }

    const int btl = tid >> 4;    // local batch (valid tid<256)
    const int dl = tid & 15;
    float gb0 = 0.f, gb1 = 0.f, gb2 = 0.f, gb3 = 0.f;
    if (tid < 256) {
      #pragma unroll
      for (int kc = 0; kc < 4; ++kc) {
        size_t base = (size_t)kc * 131072 + (size_t)(bh * 16 + btl) * 4096 + dg * 16 + dl;
        gb0 += gbasep[base + 0 * 1024];
        gb1 += gbasep[base + 1 * 1024];
        gb2 += gbasep[base + 2 * 1024];
        gb3 += gbasep[base + 3 * 1024];
      }
    }
    float cst = 0.f;

    const int arow = lane & 15;
    const int bcolr = (wid & 3) * 16 + (lane & 15);    // clamp for wid>=4 (unused dup)
    const int kg = lane >> 4;
    const int axor = arow & 7;

    __syncthreads();

    short8 breg[32];                                   // defined on ALL threads (no spill trap)
    #pragma unroll
    for (int kt = 0; kt < 32; ++kt) {
      int ca = kt * 4 + kg;
      breg[kt] = *(const short8*)&wbuf[bcolr * 1024 + ((ca ^ (bcolr & 7)) << 3)];
    }

    const int pubw = (bh * 16 + (btl & 15)) * 256 + dg * 4 + (dl >> 2);

    for (int t = 0; t < NSTEP; ++t) {
      f32x4 acc0 = {0.f, 0.f, 0.f, 0.f};
      f32x4 acc1 = {0.f, 0.f, 0.f, 0.f};
      if (wid < 4) {
        #pragma unroll
        for (int kt = 0; kt < 32; kt += 2) {
          int ca = kt * 4 + kg;
          short8 a0 = *(const short8*)&hbuf[arow * 1024 + ((ca ^ axor) << 3)];
          acc0 = __builtin_amdgcn_mfma_f32_16x16x32_bf16(a0, breg[kt], acc0, 0, 0, 0);
          short8 a1 = *(const short8*)&hbuf[arow * 1024 + (((ca + 4) ^ axor) << 3)];
          acc1 = __builtin_amdgcn_mfma_f32_16x16x32_bf16(a1, breg[kt + 1], acc1, 0, 0, 0);
        }
        acc0 = acc0 + acc1;
      }
      __syncthreads();
      if (wid < 4) {
        int bq = (lane >> 4) << 2;
        #pragma unroll
        for (int q = 0; q < 4; ++q) gex[(bq + q) * 68 + bcolr] = acc0[q];
      }
      __syncthreads();   // S1

      if (tid < 256) {
        float gi = gex[btl * 68 + 0  + dl] + gb0;
        float gf = gex[btl * 68 + 16 + dl] + gb1;
        float gg = gex[btl * 68 + 32 + dl] + gb2;
        float go = gex[btl * 68 + 48 + dl] + gb3;
        float si = 1.f / (1.f + __expf(-gi));
        float sf = 1.f / (1.f + __expf(-gf));
        float so = 1.f / (1.f + __expf(-go));
        cst = sf * cst + si * tanhf(gg);
        float h = so * tanhf(cst);
        float h1 = __shfl_down(h, 1);
        float h2 = __shfl_down(h, 2);
        float h3 = __shfl_down(h, 3);
        if ((dl & 3) == 0) {
          __hip_bfloat16 q0 = __float2bfloat16(h), q1 = __float2bfloat16(h1);
          __hip_bfloat16 q2 = __float2bfloat16(h2), q3 = __float2bfloat16(h3);
          unsigned long long v = (unsigned long long)*(uint16_t*)&q0
                               | ((unsigned long long)*(uint16_t*)&q1 << 16)
                               | ((unsigned long long)*(uint16_t*)&q2 << 32)
                               | ((unsigned long long)*(uint16_t*)&q3 << 48);
          __hip_atomic_store(&Hq[(size_t)t * 8192 + pubw], v,
                             __ATOMIC_RELAXED, __HIP_MEMORY_SCOPE_AGENT);
        }
      }

      if (t == NSTEP - 1) break;

      // poll own 16 batch rows: 8 words/thread (512 threads)
      {
        const unsigned long long* src = Hq + (size_t)t * 8192 + (size_t)bh * 4096;
        for (;;) {
          unsigned long long v[8];
          #pragma unroll
          for (int j = 0; j < 8; ++j) v[j] = aload(&src[j * 512 + tid]);
          int nready = 0;
          #pragma unroll
          for (int j = 0; j < 8; ++j) {
            if (v[j] != SENT) {
              int w = j * 512 + tid;
              int row = w >> 8, c = w & 255;
              int off = (((c >> 1) ^ (row & 7)) << 3) + ((c & 1) << 2);
              *(uint2*)&hbuf[row * 1024 + off] = *(uint2*)&v[j];
              ++nready;
            }
          }
          if (nready == 8) break;
          __builtin_amdgcn_s_sleep(1);
        }
      }
      __syncthreads();   // S2: step t fully visible (this block verified its half)
      if (dg == 0 && tid == 0)
        __hip_atomic_store(&ctl[bh], (uint32_t)(t + 1), __ATOMIC_RELAXED, __HIP_MEMORY_SCOPE_AGENT);
    }

    // rep blocks verify step 98 of their half, then signal all-done
    if (dg == 0) {
      const unsigned long long* src = Hq + (size_t)98 * 8192 + (size_t)bh * 4096;
      for (;;) {
        int nready = 0;
        #pragma unroll
        for (int j = 0; j < 8; ++j)
          if (aload(&src[j * 512 + tid]) != SENT) ++nready;
        if (nready == 8) break;
        __builtin_amdgcn_s_sleep(1);
      }
      __syncthreads();
      if (tid == 0)
        __hip_atomic_store(&ctl[bh], 1000u, __ATOMIC_RELAXED, __HIP_MEMORY_SCOPE_AGENT);
    }
    __syncthreads();   // LDS free for GEMM phase
  }

  // ============ GEMM consumer: 256x128 tiles from gated work queue ============
  {
    __hip_bfloat16* As = (__hip_bfloat16*)lds;             // [2][256*64] = 64 KB
    __hip_bfloat16* Bs = (__hip_bfloat16*)(lds + 65536);   // [2][128*64] = 32 KB
    volatile int* bc = (volatile int*)(lds + 98304);

    if (tid == 0) {
      while (__hip_atomic_load(&ctl[2], __ATOMIC_RELAXED, __HIP_MEMORY_SCOPE_AGENT) < 128u)
        __builtin_amdgcn_s_sleep(8);
    }
    __syncthreads();
    __threadfence();   // acquire: local caches refetch WT

    const int wm = wid >> 1;       // 0..3  (M 64-band)
    const int wn = wid & 1;        // 0..1  (N 64-band)
    const int kg = lane >> 4;

    // B staging constants (2 chunks/thread)
    int brr[2], bso[2];
    #pragma unroll
    for (int j = 0; j < 2; ++j) {
      int c = j * 512 + tid;
      int r = c >> 3;
      brr[j] = r;
      bso[j] = ((c & 7) ^ (r & 7)) * 8;
    }
    // A staging constants (4 chunks/thread, via atomics)
    int alr[4], asl[4];
    #pragma unroll
    for (int j = 0; j < 4; ++j) {
      int c = j * 512 + tid;
      alr[j] = c >> 3;             // local row 0..255
      asl[j] = c & 7;              // slot
    }
    const int ldsb = (tid & 448) * 8;   // wave-uniform elem base (64 chunks/wave/issue)

    for (;;) {
      if (tid == 0) *bc = (int)atomicAdd(&ctl[3], 1u);
      __syncthreads();
      int it = *bc;
      __syncthreads();
      if (it >= NITEMS) break;
      int g = it / 250;
      int nt = it - g * 250;
      const int mbase = g * 256;
      const int nbase = nt * 128;
      uint32_t need = (uint32_t)(8 * g + 8 < 99 ? 8 * g + 8 : 99);
      if (tid == 0) {
        for (;;) {
          uint32_t c0 = __hip_atomic_load(&ctl[0], __ATOMIC_RELAXED, __HIP_MEMORY_SCOPE_AGENT);
          uint32_t c1 = __hip_atomic_load(&ctl[1], __ATOMIC_RELAXED, __HIP_MEMORY_SCOPE_AGENT);
          if (c0 >= need && c1 >= need) break;
          __builtin_amdgcn_s_sleep(16);
        }
      }
      __syncthreads();

      int agr[4];                  // global A rows (clamped into zeroed pad)
      #pragma unroll
      for (int j = 0; j < 4; ++j) agr[j] = min(mbase + alr[j], MPAD - 1);

      f32x4 acc[4][4];
      #pragma unroll
      for (int m = 0; m < 4; ++m)
        #pragma unroll
        for (int n = 0; n < 4; ++n) acc[m][n] = (f32x4){0.f, 0.f, 0.f, 0.f};

      unsigned long long av[8];
      auto SB = [&](int nb, int kt) {
        #pragma unroll
        for (int j = 0; j < 2; ++j)
          gload_lds16(WT + (size_t)(nbase + brr[j]) * 1024 + kt * 64 + bso[j],
                      Bs + nb * 8192 + j * 4096 + ldsb);
      };
      auto ALOAD = [&](int kt) {
        #pragma unroll
        for (int j = 0; j < 4; ++j) {
          size_t gw = (size_t)agr[j] * 256 + kt * 16 + asl[j] * 2;
          av[2 * j]     = aload(&Hq[gw]);
          av[2 * j + 1] = aload(&Hq[gw + 1]);
        }
      };
      auto AWRITE = [&](int nb) {
        #pragma unroll
        for (int j = 0; j < 4; ++j) {
          uint4 w;
          w.x = (uint32_t)av[2 * j];     w.y = (uint32_t)(av[2 * j] >> 32);
          w.z = (uint32_t)av[2 * j + 1]; w.w = (uint32_t)(av[2 * j + 1] >> 32);
          *(uint4*)&As[nb * 16384 + alr[j] * 64 + ((asl[j] ^ (alr[j] & 7)) << 3)] = w;
        }
      };
      auto COMPUTE = [&](int nb) {
        __builtin_amdgcn_s_setprio(1);
        #pragma unroll
        for (int kk = 0; kk < 2; ++kk) {
          const int slot = kk * 4 + kg;
          short8 a[4], b[4];
          #pragma unroll
          for (int m = 0; m < 4; ++m) {
            int r = wm * 64 + m * 16 + (lane & 15);
            a[m] = *(const short8*)&As[nb * 16384 + r * 64 + ((slot ^ (r & 7)) << 3)];
          }
          #pragma unroll
          for (int n = 0; n < 4; ++n) {
            int r = wn * 64 + n * 16 + (lane & 15);
            b[n] = *(const short8*)&Bs[nb * 8192 + r * 64 + ((slot ^ (r & 7)) << 3)];
          }
          #pragma unroll
          for (int m = 0; m < 4; ++m)
            #pragma unroll
            for (int n = 0; n < 4; ++n)
              acc[m][n] = __builtin_amdgcn_mfma_f32_16x16x32_bf16(a[m], b[n], acc[m][n], 0, 0, 0);
        }
        __builtin_amdgcn_s_setprio(0);
      };

      // prologue
      SB(0, 0);
      ALOAD(0);
      asm volatile("s_waitcnt vmcnt(0)" ::: "memory");
      AWRITE(0);
      asm volatile("s_waitcnt lgkmcnt(0)" ::: "memory");
      __builtin_amdgcn_s_barrier();
      for (int kt = 0; kt < 16; ++kt) {
        int cur = kt & 1;
        if (kt < 15) { SB(cur ^ 1, kt + 1); ALOAD(kt + 1); }
        COMPUTE(cur);
        asm volatile("s_waitcnt vmcnt(0)" ::: "memory");
        if (kt < 15) AWRITE(cur ^ 1);
        asm volatile("s_waitcnt lgkmcnt(0)" ::: "memory");
        __builtin_amdgcn_s_barrier();
      }

      if (g != 12) {
        #pragma unroll
        for (int n = 0; n < 4; ++n) {
          int gcol = nbase + wn * 64 + n * 16 + (lane & 15);
          float bl = b_lm[gcol];
          #pragma unroll
          for (int m = 0; m < 4; ++m) {
            int rbase = mbase + wm * 64 + m * 16 + ((lane >> 4) << 2);
            #pragma unroll
            for (int q = 0; q < 4; ++q)
              __builtin_nontemporal_store(acc[m][n][q] + bl,
                  &out[(size_t)(rbase + q + 32) * V_ + gcol]);
          }
        }
      } else {
        #pragma unroll
        for (int n = 0; n < 4; ++n) {
          int gcol = nbase + wn * 64 + n * 16 + (lane & 15);
          float bl = b_lm[gcol];
          #pragma unroll
          for (int m = 0; m < 4; ++m) {
            int rbase = mbase + wm * 64 + m * 16 + ((lane >> 4) << 2);
            #pragma unroll
            for (int q = 0; q < 4; ++q) {
              int r = rbase + q;
              if (r < MROWS)
                __builtin_nontemporal_store(acc[m][n][q] + bl,
                    &out[(size_t)(r + 32) * V_ + gcol]);
            }
          }
        }
      }
    }
  }
}

extern "C" void kernel_launch(void* const* d_in, const int* in_sizes, int n_in,
                              void* d_out, int out_size, void* d_ws, size_t ws_size,
                              hipStream_t stream) {
  const float* features = (const float*)d_in[0];
  // d_in[1]=W_fk, d_in[2]=b_fk, d_in[5]=W_tk, d_in[6]=b_tk : dead code (softmax over size-1 axis)
  const float* W_fv = (const float*)d_in[3];
  const float* b_fv = (const float*)d_in[4];
  const float* W_ih = (const float*)d_in[7];
  const float* W_hh = (const float*)d_in[8];
  const float* b_ih = (const float*)d_in[9];
  const float* b_hh = (const float*)d_in[10];
  const float* W_lm = (const float*)d_in[11];
  const float* b_lm = (const float*)d_in[12];
  const float* bos  = (const float*)d_in[13];
  float* out = (float*)d_out;
  char* ws = (char*)d_ws;

  __hip_bfloat16* WT     = (__hip_bfloat16*)(ws + OFF_WT);
  unsigned long long* Hq = (unsigned long long*)(ws + OFF_H);
  float* fsum            = (float*)(ws + OFF_FSUM);
  float* ctxp            = (float*)(ws + OFF_CTXP);
  float* gbasep          = (float*)(ws + OFF_GBASEP);
  uint32_t* ctl          = (uint32_t*)(ws + OFF_CTL);

  hipLaunchKernelGGL(k_fsum,  dim3(384),       dim3(256), 0, stream, features, fsum, Hq);
  hipLaunchKernelGGL(k_ctx,   dim3(16, 2, 2),  dim3(256), 0, stream, fsum, W_fv, b_fv, ctxp);
  hipLaunchKernelGGL(k_gbase, dim3(16, 2, 4),  dim3(256), 0, stream, ctxp, W_ih, b_ih, b_hh, gbasep);
  hipMemsetAsync(ctl, 0, 64, stream);
  // one fused persistent kernel: rec + workers + gated GEMM queue (no separate k_gemm)
  hipLaunchKernelGGL(k_rec,   dim3(256), dim3(512), 163840, stream,
                     gbasep, W_hh, bos, Hq, W_lm, WT, b_lm, out, ctl);
}

// Round 16
// 763.318 us; speedup vs baseline: 1.0307x; 1.0307x over previous
//
#include <hip/hip_runtime.h>
#include <hip/hip_bf16.h>
#include <stdint.h>

typedef __attribute__((ext_vector_type(8))) short short8;
typedef __attribute__((ext_vector_type(4))) float f32x4;

#define B_ 32
#define N_ 196
#define D_ 1024
#define V_ 32000
#define NSTEP 99
#define MROWS 3168   // 99*32
#define MPAD  3200
#define SENT  0x7FC07FC07FC07FC0ULL   // 4x bf16 NaN: unreachable as packed h (|h|<1)

// workspace layout (bytes)
#define OFF_WT     0ULL          // bf16 [32000][1024]  = 65,536,000
#define OFF_H      65536000ULL   // bf16 [3200][1024]   =  6,553,600  (u64 view: [99][8192] + pad)
#define OFF_FSUM   72089600ULL   // f32  [32][1024]
#define OFF_CTXP   72220672ULL   // f32  [2][32][1024]  partials
#define OFF_GBASEP 72482816ULL   // f32  [4][32][4096]  partials

#define AS3 __attribute__((address_space(3)))
#define AS1 __attribute__((address_space(1)))
static __device__ __forceinline__ void gload_lds16(const void* g, void* l) {
  __builtin_amdgcn_global_load_lds((const AS1 uint32_t*)g, (AS3 uint32_t*)l, 16, 0, 0);
}

// ---------------- fsum (blocks 0..127) + sentinel-fill H (blocks 128..383) ----------------
__global__ void k_fsum(const float* __restrict__ feat, float* __restrict__ fsum,
                       unsigned long long* __restrict__ Hq) {
  if (blockIdx.x >= 128) {
    int gid = (blockIdx.x - 128) * 256 + threadIdx.x;   // 65536 threads
    for (int w = gid; w < NSTEP * 8192; w += 65536) Hq[w] = SENT;
    return;
  }
  int idx = blockIdx.x * 256 + threadIdx.x;           // 32768
  int b = idx >> 10, e = idx & 1023;
  const float* p = feat + (size_t)b * (N_ * D_) + e;
  float s = 0.f;
  #pragma unroll 4
  for (int n = 0; n < N_; ++n) s += fmaxf(p[(size_t)n * D_], 0.f);
  fsum[idx] = s;
}

// ---------------- ctxp[kc] = fsum[:,e-chunk] @ W_fv[e-chunk,:] (+196*b_fv in kc0) ----------------
// split-K: grid (16, 2, 2) = 64 blocks
__global__ void k_ctx(const float* __restrict__ fsum, const float* __restrict__ W_fv,
                      const float* __restrict__ b_fv, float* __restrict__ ctxp) {
  __shared__ float fs[16][512];                       // 32 KB
  int kc = blockIdx.z;                                // e-chunk 0..1
  int e0 = kc * 512;
  int b0 = blockIdx.y * 16;
  int d = blockIdx.x * 64 + (threadIdx.x & 63);
  int bq = threadIdx.x >> 6;                          // 4 batch-quads
  for (int i = threadIdx.x; i < 8192; i += 256)
    fs[i >> 9][i & 511] = fsum[(b0 + (i >> 9)) * 1024 + e0 + (i & 511)];
  __syncthreads();
  float bias = (kc == 0) ? 196.f * b_fv[d] : 0.f;
  float acc[4] = {bias, bias, bias, bias};
  for (int e4 = 0; e4 < 128; ++e4) {
    float w0 = W_fv[(size_t)(e0 + 4 * e4 + 0) * 1024 + d];
    float w1 = W_fv[(size_t)(e0 + 4 * e4 + 1) * 1024 + d];
    float w2 = W_fv[(size_t)(e0 + 4 * e4 + 2) * 1024 + d];
    float w3 = W_fv[(size_t)(e0 + 4 * e4 + 3) * 1024 + d];
    #pragma unroll
    for (int r = 0; r < 4; ++r) {
      float4 c = *(const float4*)&fs[bq * 4 + r][e4 * 4];
      acc[r] = fmaf(c.x, w0, fmaf(c.y, w1, fmaf(c.z, w2, fmaf(c.w, w3, acc[r]))));
    }
  }
  #pragma unroll
  for (int r = 0; r < 4; ++r)
    ctxp[kc * 32768 + (size_t)(b0 + bq * 4 + r) * 1024 + d] = acc[r];
}

// ---------------- gbasep[kc] = ctx[:,e-chunk] @ W_ih[e-chunk,:] (+biases in kc0) ----------------
// split-K: grid (16, 2, 4) = 128 blocks; ctx = sum of 2 ctx partials (fused here)
__global__ void k_gbase(const float* __restrict__ ctxp, const float* __restrict__ W_ih,
                        const float* __restrict__ b_ih, const float* __restrict__ b_hh,
                        float* __restrict__ gbasep) {
  __shared__ float cs[16][256];                       // 16 KB
  int kc = blockIdx.z;                                // e-chunk 0..3
  int e0 = kc * 256;
  int b0 = blockIdx.y * 16;
  int j = blockIdx.x * 256 + threadIdx.x;
  for (int i = threadIdx.x; i < 4096; i += 256) {
    int r = i >> 8, e = i & 255;
    cs[r][e] = ctxp[(size_t)(b0 + r) * 1024 + e0 + e]
             + ctxp[32768 + (size_t)(b0 + r) * 1024 + e0 + e];
  }
  __syncthreads();
  float bias = (kc == 0) ? (b_ih[j] + b_hh[j]) : 0.f;
  float acc[16];
  #pragma unroll
  for (int r = 0; r < 16; ++r) acc[r] = bias;
  for (int e4 = 0; e4 < 64; ++e4) {
    float w0 = W_ih[(size_t)(e0 + 4 * e4 + 0) * 4096 + j];
    float w1 = W_ih[(size_t)(e0 + 4 * e4 + 1) * 4096 + j];
    float w2 = W_ih[(size_t)(e0 + 4 * e4 + 2) * 4096 + j];
    float w3 = W_ih[(size_t)(e0 + 4 * e4 + 3) * 4096 + j];
    #pragma unroll
    for (int r = 0; r < 16; ++r) {
      float4 c = *(const float4*)&cs[r][e4 * 4];
      acc[r] = fmaf(c.x, w0, fmaf(c.y, w1, fmaf(c.z, w2, fmaf(c.w, w3, acc[r]))));
    }
  }
  #pragma unroll
  for (int r = 0; r < 16; ++r)
    gbasep[kc * 131072 + (size_t)(b0 + r) * 4096 + j] = acc[r];
}

// ---------------- persistent LSTM recurrence (blocks 0..127) + workers (128..255) ----------------
// 2-D decomposition (round-12/13/14 validated): block (bh,dg) owns 16 batches x 16 dims.
// gex double-buffered by step parity -> 2 barriers/step (pre-write barrier removed).
__global__ __launch_bounds__(256, 1) void k_rec(
    const float* __restrict__ gbasep, const float* __restrict__ W_hh,
    const float* __restrict__ bos, unsigned long long* __restrict__ Hq,
    const float* __restrict__ W_lm, __hip_bfloat16* __restrict__ WT,
    float* __restrict__ out) {
  extern __shared__ char lds[];
  const int tid = threadIdx.x;
  const int blk = blockIdx.x;

  if (blk >= 128) {
    // ---------- worker blocks ----------
    __hip_bfloat16* t = (__hip_bfloat16*)lds;          // [64][66]
    int wblk = blk - 128;
    for (int idx = wblk * 256 + tid; idx < B_ * V_; idx += 128 * 256)
      __builtin_nontemporal_store(((idx % V_) == 0) ? 1.0f : 0.0f, &out[idx]);
    // zero TRUE pad rows 3168..3199 (256 u64 per row)
    if (wblk < 64) ((uint32_t*)(Hq + (size_t)MROWS * 256))[wblk * 256 + tid] = 0u;
    int tx = tid & 63, ty = tid >> 6;
    int word = tx & 31, nh = tx >> 5;
    for (int tile = wblk; tile < 8000; tile += 128) {
      int k0 = (tile & 15) * 64;
      int n0 = (tile >> 4) * 64;
      __syncthreads();
      #pragma unroll
      for (int i = 0; i < 16; ++i) {
        int r = i * 4 + ty;
        t[r * 66 + tx] = __float2bfloat16(
            __builtin_nontemporal_load(&W_lm[(size_t)(k0 + r) * V_ + n0 + tx]));
      }
      __syncthreads();
      #pragma unroll
      for (int i = 0; i < 8; ++i) {
        int n = i * 8 + ty * 2 + nh;
        uint32_t lo = *(const uint16_t*)&t[2 * word * 66 + n];
        uint32_t hi = *(const uint16_t*)&t[(2 * word + 1) * 66 + n];
        __builtin_nontemporal_store(lo | (hi << 16),
            (uint32_t*)&WT[(size_t)(n0 + n) * 1024 + k0] + word);
      }
    }
    return;
  }

  // ---------- recurrence blocks ----------
  __hip_bfloat16* hbuf = (__hip_bfloat16*)lds;             // [16][1024] swizzled (32 KB)
  __hip_bfloat16* wbuf = (__hip_bfloat16*)(lds + 32768);   // [64][1024] (init only, 128 KB)
  float* gexb = (float*)(lds + 32768);                     // [2][16][68] f32, aliases wbuf

  const int bh = blk >> 6;     // batch half 0..1
  const int dg = blk & 63;     // dim group 0..63 (dims dg*16..+16)

  for (int idx = tid; idx < 64 * 1024; idx += 256) {
    int c = idx & 63;
    int k = idx >> 6;
    float w = W_hh[(size_t)k * 4096 + (c >> 4) * 1024 + dg * 16 + (c & 15)];
    wbuf[c * 1024 + ((((k >> 3) ^ (c & 7)) << 3) | (k & 7))] = __float2bfloat16(w);
  }
  for (int idx = tid; idx < 16 * 1024; idx += 256) {
    int row = idx >> 10;
    int k = idx & 1023;
    hbuf[row * 1024 + ((((k >> 3) ^ (row & 7)) << 3) | (k & 7))] = __float2bfloat16(bos[k]);
  }

  const int btl = tid >> 4;    // local batch 0..15
  const int dl = tid & 15;     // local dim 0..15
  float gb0 = 0.f, gb1 = 0.f, gb2 = 0.f, gb3 = 0.f;
  #pragma unroll
  for (int kc = 0; kc < 4; ++kc) {
    size_t base = (size_t)kc * 131072 + (size_t)(bh * 16 + btl) * 4096 + dg * 16 + dl;
    gb0 += gbasep[base + 0 * 1024];
    gb1 += gbasep[base + 1 * 1024];
    gb2 += gbasep[base + 2 * 1024];
    gb3 += gbasep[base + 3 * 1024];
  }
  float cst = 0.f;

  const int lane = tid & 63;
  const int wid = tid >> 6;          // 0..3 : wave owns local cols wid*16..+16
  const int arow = lane & 15;        // batch row (single 16-row tile)
  const int bcol = wid * 16 + (lane & 15);
  const int kg = lane >> 4;
  const int axor = arow & 7;

  __syncthreads();

  short8 breg[32];
  #pragma unroll
  for (int kt = 0; kt < 32; ++kt) {
    int ca = kt * 4 + kg;
    breg[kt] = *(const short8*)&wbuf[bcol * 1024 + ((ca ^ (bcol & 7)) << 3)];
  }

  const int pubw = (bh * 16 + btl) * 256 + dg * 4 + (dl >> 2);

  for (int t = 0; t < NSTEP; ++t) {
    float* gex = gexb + (t & 1) * (16 * 68);   // parity buffer: no pre-write barrier needed
    f32x4 acc0 = {0.f, 0.f, 0.f, 0.f};
    f32x4 acc1 = {0.f, 0.f, 0.f, 0.f};
    #pragma unroll
    for (int kt = 0; kt < 32; kt += 2) {
      int ca = kt * 4 + kg;
      short8 a0 = *(const short8*)&hbuf[arow * 1024 + ((ca ^ axor) << 3)];
      acc0 = __builtin_amdgcn_mfma_f32_16x16x32_bf16(a0, breg[kt], acc0, 0, 0, 0);
      short8 a1 = *(const short8*)&hbuf[arow * 1024 + (((ca + 4) ^ axor) << 3)];
      acc1 = __builtin_amdgcn_mfma_f32_16x16x32_bf16(a1, breg[kt + 1], acc1, 0, 0, 0);
    }
    acc0 = acc0 + acc1;
    {
      int bq = (lane >> 4) << 2;
      #pragma unroll
      for (int q = 0; q < 4; ++q) gex[(bq + q) * 68 + bcol] = acc0[q];
    }
    __syncthreads();   // S1: gex[t&1] written by all waves

    float gi = gex[btl * 68 + 0  + dl] + gb0;
    float gf = gex[btl * 68 + 16 + dl] + gb1;
    float gg = gex[btl * 68 + 32 + dl] + gb2;
    float go = gex[btl * 68 + 48 + dl] + gb3;
    float si = 1.f / (1.f + __expf(-gi));
    float sf = 1.f / (1.f + __expf(-gf));
    float so = 1.f / (1.f + __expf(-go));
    cst = sf * cst + si * tanhf(gg);
    float h = so * tanhf(cst);

    float h1 = __shfl_down(h, 1);
    float h2 = __shfl_down(h, 2);
    float h3 = __shfl_down(h, 3);
    if ((dl & 3) == 0) {
      __hip_bfloat16 q0 = __float2bfloat16(h), q1 = __float2bfloat16(h1);
      __hip_bfloat16 q2 = __float2bfloat16(h2), q3 = __float2bfloat16(h3);
      unsigned long long v = (unsigned long long)*(uint16_t*)&q0
                           | ((unsigned long long)*(uint16_t*)&q1 << 16)
                           | ((unsigned long long)*(uint16_t*)&q2 << 32)
                           | ((unsigned long long)*(uint16_t*)&q3 << 48);
      __hip_atomic_store(&Hq[(size_t)t * 8192 + pubw], v,
                         __ATOMIC_RELAXED, __HIP_MEMORY_SCOPE_AGENT);
    }

    if (t == NSTEP - 1) break;

    // poll own 16 batch rows of H[t]: 16 words/thread, unconditional batched loads
    {
      const unsigned long long* src = Hq + (size_t)t * 8192 + (size_t)bh * 16 * 256;
      for (;;) {
        unsigned long long v[16];
        #pragma unroll
        for (int j = 0; j < 16; ++j)
          v[j] = __hip_atomic_load(&src[j * 256 + tid],
                                   __ATOMIC_RELAXED, __HIP_MEMORY_SCOPE_AGENT);
        int nready = 0;
        #pragma unroll
        for (int j = 0; j < 16; ++j) {
          if (v[j] != SENT) {
            int off = (((tid >> 1) ^ (j & 7)) << 3) + ((tid & 1) << 2);
            *(uint2*)&hbuf[j * 1024 + off] = *(uint2*)&v[j];
            ++nready;
          }
        }
        if (nready == 16) break;
        __builtin_amdgcn_s_sleep(1);
      }
    }
    __syncthreads();   // S2: hbuf fully deposited
  }
}

// ---------------- logits GEMM: 256x256, ONE-barrier dbuf loop, NT epilogue (round-14) ----------------
__global__ __launch_bounds__(512, 1) void k_gemm(
    const __hip_bfloat16* __restrict__ H,    // [3200][1024] (rows 3168..3199 zero)
    const __hip_bfloat16* __restrict__ WT,   // [32000][1024]
    const float* __restrict__ b_lm,
    float* __restrict__ out) {
  extern __shared__ char glds[];
  __hip_bfloat16* As = (__hip_bfloat16*)glds;            // [2][256*64] = 64 KB
  __hip_bfloat16* Bs = (__hip_bfloat16*)(glds + 65536);  // [2][256*64] = 64 KB

  // XCD-bijective remap: nwg = 1625 = 8*203 + 1
  int bid = blockIdx.x;
  int xcd = bid & 7;
  int idx = bid >> 3;
  int wg = (xcd < 1 ? xcd * 204 : 204 + (xcd - 1) * 203) + idx;
  // GM=13 raster: all 13 m-tiles consecutive per B panel (nt), mt fastest
  int nt = wg / 13;            // 0..124
  int mt = wg - nt * 13;       // 0..12
  const int mbase = mt * 256;
  const int nbase = nt * 256;

  const int tid = threadIdx.x;
  const int lane = tid & 63;
  const int wid = tid >> 6;      // 0..7
  const int wm = wid >> 2;       // 0..1  (M 128-half)
  const int wn = wid & 3;        // 0..3  (N 64-quarter)

  f32x4 acc[8][4];
  #pragma unroll
  for (int m = 0; m < 8; ++m)
    #pragma unroll
    for (int n = 0; n < 4; ++n) acc[m][n] = (f32x4){0.f, 0.f, 0.f, 0.f};

  const int kg = lane >> 4;

  int srowA[4], srowB[4], soff[4];
  #pragma unroll
  for (int j = 0; j < 4; ++j) {
    int c = j * 512 + tid;
    int row = c >> 3;
    srowB[j] = nbase + row;
    srowA[j] = min(mbase + row, MPAD - 1);   // clamp pad rows (zeros)
    soff[j] = ((c & 7) ^ (row & 7)) * 8;
  }
  const int ldsbase = (tid & 448) * 8;

  auto STAGE = [&](int nb, int kt) {
    #pragma unroll
    for (int j = 0; j < 4; ++j)
      gload_lds16(H + (size_t)srowA[j] * 1024 + kt * 64 + soff[j],
                  As + nb * 16384 + j * 4096 + ldsbase);
    #pragma unroll
    for (int j = 0; j < 4; ++j)
      gload_lds16(WT + (size_t)srowB[j] * 1024 + kt * 64 + soff[j],
                  Bs + nb * 16384 + j * 4096 + ldsbase);
  };
  auto COMPUTE = [&](int nb) {
    __builtin_amdgcn_s_setprio(1);
    #pragma unroll
    for (int kk = 0; kk < 2; ++kk) {
      const int slot = kk * 4 + kg;
      short8 a[8], b[4];
      #pragma unroll
      for (int m = 0; m < 8; ++m) {
        int r = wm * 128 + m * 16 + (lane & 15);
        a[m] = *(const short8*)&As[nb * 16384 + r * 64 + ((slot ^ (r & 7)) << 3)];
      }
      #pragma unroll
      for (int n = 0; n < 4; ++n) {
        int r = wn * 64 + n * 16 + (lane & 15);
        b[n] = *(const short8*)&Bs[nb * 16384 + r * 64 + ((slot ^ (r & 7)) << 3)];
      }
      #pragma unroll
      for (int m = 0; m < 8; ++m)
        #pragma unroll
        for (int n = 0; n < 4; ++n)
          acc[m][n] = __builtin_amdgcn_mfma_f32_16x16x32_bf16(a[m], b[n], acc[m][n], 0, 0, 0);
    }
    __builtin_amdgcn_s_setprio(0);
  };

  STAGE(0, 0);
  asm volatile("s_waitcnt vmcnt(0)" ::: "memory");
  __builtin_amdgcn_s_barrier();
  for (int kt = 0; kt < 16; ++kt) {
    if (kt < 15) STAGE((kt + 1) & 1, kt + 1);
    COMPUTE(kt & 1);
    asm volatile("s_waitcnt vmcnt(0)" ::: "memory");
    __builtin_amdgcn_s_barrier();
  }

  if (mt != 12) {
    #pragma unroll
    for (int n = 0; n < 4; ++n) {
      int gcol = nbase + wn * 64 + n * 16 + (lane & 15);
      float bl = b_lm[gcol];
      #pragma unroll
      for (int m = 0; m < 8; ++m) {
        int rbase = mbase + wm * 128 + m * 16 + ((lane >> 4) << 2);
        #pragma unroll
        for (int q = 0; q < 4; ++q)
          __builtin_nontemporal_store(acc[m][n][q] + bl,
              &out[(size_t)(rbase + q + 32) * V_ + gcol]);
      }
    }
  } else {
    #pragma unroll
    for (int n = 0; n < 4; ++n) {
      int gcol = nbase + wn * 64 + n * 16 + (lane & 15);
      float bl = b_lm[gcol];
      #pragma unroll
      for (int m = 0; m < 8; ++m) {
        int rbase = mbase + wm * 128 + m * 16 + ((lane >> 4) << 2);
        #pragma unroll
        for (int q = 0; q < 4; ++q) {
          int r = rbase + q;
          if (r < MROWS)
            __builtin_nontemporal_store(acc[m][n][q] + bl,
                &out[(size_t)(r + 32) * V_ + gcol]);
        }
      }
    }
  }
}

extern "C" void kernel_launch(void* const* d_in, const int* in_sizes, int n_in,
                              void* d_out, int out_size, void* d_ws, size_t ws_size,
                              hipStream_t stream) {
  const float* features = (const float*)d_in[0];
  // d_in[1]=W_fk, d_in[2]=b_fk, d_in[5]=W_tk, d_in[6]=b_tk : dead code (softmax over size-1 axis)
  const float* W_fv = (const float*)d_in[3];
  const float* b_fv = (const float*)d_in[4];
  const float* W_ih = (const float*)d_in[7];
  const float* W_hh = (const float*)d_in[8];
  const float* b_ih = (const float*)d_in[9];
  const float* b_hh = (const float*)d_in[10];
  const float* W_lm = (const float*)d_in[11];
  const float* b_lm = (const float*)d_in[12];
  const float* bos  = (const float*)d_in[13];
  float* out = (float*)d_out;
  char* ws = (char*)d_ws;

  __hip_bfloat16* WT     = (__hip_bfloat16*)(ws + OFF_WT);
  __hip_bfloat16* H      = (__hip_bfloat16*)(ws + OFF_H);
  unsigned long long* Hq = (unsigned long long*)(ws + OFF_H);
  float* fsum            = (float*)(ws + OFF_FSUM);
  float* ctxp            = (float*)(ws + OFF_CTXP);
  float* gbasep          = (float*)(ws + OFF_GBASEP);

  hipLaunchKernelGGL(k_fsum,  dim3(384),       dim3(256), 0, stream, features, fsum, Hq);
  hipLaunchKernelGGL(k_ctx,   dim3(16, 2, 2),  dim3(256), 0, stream, fsum, W_fv, b_fv, ctxp);
  hipLaunchKernelGGL(k_gbase, dim3(16, 2, 4),  dim3(256), 0, stream, ctxp, W_ih, b_ih, b_hh, gbasep);
  // blocks 0..127: recurrence; 128..255: one-hot + pad zero + W_lm->WT (concurrent, NT)
  hipLaunchKernelGGL(k_rec,   dim3(256),  dim3(256), 163840, stream,
                     gbasep, W_hh, bos, Hq, W_lm, WT, out);
  hipLaunchKernelGGL(k_gemm,  dim3(1625), dim3(512), 131072, stream, H, WT, b_lm, out);
}

// Round 17
// 749.067 us; speedup vs baseline: 1.0503x; 1.0190x over previous
//
#include <hip/hip_runtime.h>
#include <hip/hip_bf16.h>
#include <stdint.h>

typedef __attribute__((ext_vector_type(8))) short short8;
typedef __attribute__((ext_vector_type(4))) float f32x4;

#define B_ 32
#define N_ 196
#define D_ 1024
#define V_ 32000
#define NSTEP 99
#define MROWS 3168   // 99*32
#define MPAD  3200
#define SENT  0x7FC07FC07FC07FC0ULL   // 4x bf16 NaN: unreachable as packed h (|h|<1)

// workspace layout (bytes)
#define OFF_WT     0ULL          // bf16 [32000][1024]  = 65,536,000
#define OFF_H      65536000ULL   // bf16 [3200][1024]   =  6,553,600  (u64 view: [99][8192] + pad)
#define OFF_FSUM   72089600ULL   // f32  [32][1024]
#define OFF_CTXP   72220672ULL   // f32  [2][32][1024]  partials
#define OFF_GBASEP 72482816ULL   // f32  [4][32][4096]  partials

#define AS3 __attribute__((address_space(3)))
#define AS1 __attribute__((address_space(1)))
static __device__ __forceinline__ void gload_lds16(const void* g, void* l) {
  __builtin_amdgcn_global_load_lds((const AS1 uint32_t*)g, (AS3 uint32_t*)l, 16, 0, 0);
}

// ---------------- fsum (blocks 0..127) + sentinel-fill H (blocks 128..383) ----------------
__global__ void k_fsum(const float* __restrict__ feat, float* __restrict__ fsum,
                       unsigned long long* __restrict__ Hq) {
  if (blockIdx.x >= 128) {
    int gid = (blockIdx.x - 128) * 256 + threadIdx.x;   // 65536 threads
    for (int w = gid; w < NSTEP * 8192; w += 65536) Hq[w] = SENT;
    return;
  }
  int idx = blockIdx.x * 256 + threadIdx.x;           // 32768
  int b = idx >> 10, e = idx & 1023;
  const float* p = feat + (size_t)b * (N_ * D_) + e;
  float s = 0.f;
  #pragma unroll 4
  for (int n = 0; n < N_; ++n) s += fmaxf(p[(size_t)n * D_], 0.f);
  fsum[idx] = s;
}

// ---------------- ctxp[kc] = fsum[:,e-chunk] @ W_fv[e-chunk,:] (+196*b_fv in kc0) ----------------
// split-K: grid (16, 2, 2) = 64 blocks
__global__ void k_ctx(const float* __restrict__ fsum, const float* __restrict__ W_fv,
                      const float* __restrict__ b_fv, float* __restrict__ ctxp) {
  __shared__ float fs[16][512];                       // 32 KB
  int kc = blockIdx.z;                                // e-chunk 0..1
  int e0 = kc * 512;
  int b0 = blockIdx.y * 16;
  int d = blockIdx.x * 64 + (threadIdx.x & 63);
  int bq = threadIdx.x >> 6;                          // 4 batch-quads
  for (int i = threadIdx.x; i < 8192; i += 256)
    fs[i >> 9][i & 511] = fsum[(b0 + (i >> 9)) * 1024 + e0 + (i & 511)];
  __syncthreads();
  float bias = (kc == 0) ? 196.f * b_fv[d] : 0.f;
  float acc[4] = {bias, bias, bias, bias};
  for (int e4 = 0; e4 < 128; ++e4) {
    float w0 = W_fv[(size_t)(e0 + 4 * e4 + 0) * 1024 + d];
    float w1 = W_fv[(size_t)(e0 + 4 * e4 + 1) * 1024 + d];
    float w2 = W_fv[(size_t)(e0 + 4 * e4 + 2) * 1024 + d];
    float w3 = W_fv[(size_t)(e0 + 4 * e4 + 3) * 1024 + d];
    #pragma unroll
    for (int r = 0; r < 4; ++r) {
      float4 c = *(const float4*)&fs[bq * 4 + r][e4 * 4];
      acc[r] = fmaf(c.x, w0, fmaf(c.y, w1, fmaf(c.z, w2, fmaf(c.w, w3, acc[r]))));
    }
  }
  #pragma unroll
  for (int r = 0; r < 4; ++r)
    ctxp[kc * 32768 + (size_t)(b0 + bq * 4 + r) * 1024 + d] = acc[r];
}

// ---------------- gbasep[kc] = ctx[:,e-chunk] @ W_ih[e-chunk,:] (+biases in kc0) ----------------
// split-K: grid (16, 2, 4) = 128 blocks; ctx = sum of 2 ctx partials (fused here)
__global__ void k_gbase(const float* __restrict__ ctxp, const float* __restrict__ W_ih,
                        const float* __restrict__ b_ih, const float* __restrict__ b_hh,
                        float* __restrict__ gbasep) {
  __shared__ float cs[16][256];                       // 16 KB
  int kc = blockIdx.z;                                // e-chunk 0..3
  int e0 = kc * 256;
  int b0 = blockIdx.y * 16;
  int j = blockIdx.x * 256 + threadIdx.x;
  for (int i = threadIdx.x; i < 4096; i += 256) {
    int r = i >> 8, e = i & 255;
    cs[r][e] = ctxp[(size_t)(b0 + r) * 1024 + e0 + e]
             + ctxp[32768 + (size_t)(b0 + r) * 1024 + e0 + e];
  }
  __syncthreads();
  float bias = (kc == 0) ? (b_ih[j] + b_hh[j]) : 0.f;
  float acc[16];
  #pragma unroll
  for (int r = 0; r < 16; ++r) acc[r] = bias;
  for (int e4 = 0; e4 < 64; ++e4) {
    float w0 = W_ih[(size_t)(e0 + 4 * e4 + 0) * 4096 + j];
    float w1 = W_ih[(size_t)(e0 + 4 * e4 + 1) * 4096 + j];
    float w2 = W_ih[(size_t)(e0 + 4 * e4 + 2) * 4096 + j];
    float w3 = W_ih[(size_t)(e0 + 4 * e4 + 3) * 4096 + j];
    #pragma unroll
    for (int r = 0; r < 16; ++r) {
      float4 c = *(const float4*)&cs[r][e4 * 4];
      acc[r] = fmaf(c.x, w0, fmaf(c.y, w1, fmaf(c.z, w2, fmaf(c.w, w3, acc[r]))));
    }
  }
  #pragma unroll
  for (int r = 0; r < 16; ++r)
    gbasep[kc * 131072 + (size_t)(b0 + r) * 4096 + j] = acc[r];
}

// ---------------- persistent LSTM recurrence (blocks 0..127) + workers (128..255) ----------------
// 2-D decomposition (validated): block (bh,dg) owns 16 batches x 16 dims.
__global__ __launch_bounds__(256, 1) void k_rec(
    const float* __restrict__ gbasep, const float* __restrict__ W_hh,
    const float* __restrict__ bos, unsigned long long* __restrict__ Hq,
    const float* __restrict__ W_lm, __hip_bfloat16* __restrict__ WT,
    float* __restrict__ out) {
  extern __shared__ char lds[];
  const int tid = threadIdx.x;
  const int blk = blockIdx.x;

  if (blk >= 128) {
    // ---------- worker blocks ----------
    __hip_bfloat16* t = (__hip_bfloat16*)lds;          // [64][66]
    int wblk = blk - 128;
    for (int idx = wblk * 256 + tid; idx < B_ * V_; idx += 128 * 256)
      __builtin_nontemporal_store(((idx % V_) == 0) ? 1.0f : 0.0f, &out[idx]);
    // zero TRUE pad rows 3168..3199 (256 u64 per row)
    if (wblk < 64) ((uint32_t*)(Hq + (size_t)MROWS * 256))[wblk * 256 + tid] = 0u;
    int tx = tid & 63, ty = tid >> 6;
    int word = tx & 31, nh = tx >> 5;
    for (int tile = wblk; tile < 8000; tile += 128) {
      int k0 = (tile & 15) * 64;
      int n0 = (tile >> 4) * 64;
      __syncthreads();
      #pragma unroll
      for (int i = 0; i < 16; ++i) {
        int r = i * 4 + ty;
        t[r * 66 + tx] = __float2bfloat16(
            __builtin_nontemporal_load(&W_lm[(size_t)(k0 + r) * V_ + n0 + tx]));
      }
      __syncthreads();
      #pragma unroll
      for (int i = 0; i < 8; ++i) {
        int n = i * 8 + ty * 2 + nh;
        uint32_t lo = *(const uint16_t*)&t[2 * word * 66 + n];
        uint32_t hi = *(const uint16_t*)&t[(2 * word + 1) * 66 + n];
        __builtin_nontemporal_store(lo | (hi << 16),
            (uint32_t*)&WT[(size_t)(n0 + n) * 1024 + k0] + word);
      }
    }
    return;
  }

  // ---------- recurrence blocks ----------
  __hip_bfloat16* hbuf = (__hip_bfloat16*)lds;             // [16][1024] swizzled (32 KB)
  __hip_bfloat16* wbuf = (__hip_bfloat16*)(lds + 32768);   // [64][1024] (init only, 128 KB)
  float* gexb = (float*)(lds + 32768);                     // [2][16][68] f32, aliases wbuf

  const int bh = blk >> 6;     // batch half 0..1
  const int dg = blk & 63;     // dim group 0..63 (dims dg*16..+16)

  for (int idx = tid; idx < 64 * 1024; idx += 256) {
    int c = idx & 63;
    int k = idx >> 6;
    float w = W_hh[(size_t)k * 4096 + (c >> 4) * 1024 + dg * 16 + (c & 15)];
    wbuf[c * 1024 + ((((k >> 3) ^ (c & 7)) << 3) | (k & 7))] = __float2bfloat16(w);
  }
  for (int idx = tid; idx < 16 * 1024; idx += 256) {
    int row = idx >> 10;
    int k = idx & 1023;
    hbuf[row * 1024 + ((((k >> 3) ^ (row & 7)) << 3) | (k & 7))] = __float2bfloat16(bos[k]);
  }

  const int btl = tid >> 4;    // local batch 0..15
  const int dl = tid & 15;     // local dim 0..15
  float gb0 = 0.f, gb1 = 0.f, gb2 = 0.f, gb3 = 0.f;
  #pragma unroll
  for (int kc = 0; kc < 4; ++kc) {
    size_t base = (size_t)kc * 131072 + (size_t)(bh * 16 + btl) * 4096 + dg * 16 + dl;
    gb0 += gbasep[base + 0 * 1024];
    gb1 += gbasep[base + 1 * 1024];
    gb2 += gbasep[base + 2 * 1024];
    gb3 += gbasep[base + 3 * 1024];
  }
  float cst = 0.f;

  const int lane = tid & 63;
  const int wid = tid >> 6;          // 0..3 : wave owns local cols wid*16..+16
  const int arow = lane & 15;        // batch row (single 16-row tile)
  const int bcol = wid * 16 + (lane & 15);
  const int kg = lane >> 4;
  const int axor = arow & 7;

  __syncthreads();

  short8 breg[32];
  #pragma unroll
  for (int kt = 0; kt < 32; ++kt) {
    int ca = kt * 4 + kg;
    breg[kt] = *(const short8*)&wbuf[bcol * 1024 + ((ca ^ (bcol & 7)) << 3)];
  }

  const int pubw = (bh * 16 + btl) * 256 + dg * 4 + (dl >> 2);

  for (int t = 0; t < NSTEP; ++t) {
    float* gex = gexb + (t & 1) * (16 * 68);   // parity buffer
    f32x4 acc0 = {0.f, 0.f, 0.f, 0.f};
    f32x4 acc1 = {0.f, 0.f, 0.f, 0.f};
    #pragma unroll
    for (int kt = 0; kt < 32; kt += 2) {
      int ca = kt * 4 + kg;
      short8 a0 = *(const short8*)&hbuf[arow * 1024 + ((ca ^ axor) << 3)];
      acc0 = __builtin_amdgcn_mfma_f32_16x16x32_bf16(a0, breg[kt], acc0, 0, 0, 0);
      short8 a1 = *(const short8*)&hbuf[arow * 1024 + (((ca + 4) ^ axor) << 3)];
      acc1 = __builtin_amdgcn_mfma_f32_16x16x32_bf16(a1, breg[kt + 1], acc1, 0, 0, 0);
    }
    acc0 = acc0 + acc1;
    {
      int bq = (lane >> 4) << 2;
      #pragma unroll
      for (int q = 0; q < 4; ++q) gex[(bq + q) * 68 + bcol] = acc0[q];
    }
    __syncthreads();   // S1: gex[t&1] written by all waves

    float gi = gex[btl * 68 + 0  + dl] + gb0;
    float gf = gex[btl * 68 + 16 + dl] + gb1;
    float gg = gex[btl * 68 + 32 + dl] + gb2;
    float go = gex[btl * 68 + 48 + dl] + gb3;
    float si = 1.f / (1.f + __expf(-gi));
    float sf = 1.f / (1.f + __expf(-gf));
    float so = 1.f / (1.f + __expf(-go));
    cst = sf * cst + si * tanhf(gg);
    float h = so * tanhf(cst);

    float h1 = __shfl_down(h, 1);
    float h2 = __shfl_down(h, 2);
    float h3 = __shfl_down(h, 3);
    if ((dl & 3) == 0) {
      __hip_bfloat16 q0 = __float2bfloat16(h), q1 = __float2bfloat16(h1);
      __hip_bfloat16 q2 = __float2bfloat16(h2), q3 = __float2bfloat16(h3);
      unsigned long long v = (unsigned long long)*(uint16_t*)&q0
                           | ((unsigned long long)*(uint16_t*)&q1 << 16)
                           | ((unsigned long long)*(uint16_t*)&q2 << 32)
                           | ((unsigned long long)*(uint16_t*)&q3 << 48);
      __hip_atomic_store(&Hq[(size_t)t * 8192 + pubw], v,
                         __ATOMIC_RELAXED, __HIP_MEMORY_SCOPE_AGENT);
    }

    if (t == NSTEP - 1) break;

    // poll own 16 batch rows of H[t]: 16 words/thread, unconditional batched loads
    {
      const unsigned long long* src = Hq + (size_t)t * 8192 + (size_t)bh * 16 * 256;
      for (;;) {
        unsigned long long v[16];
        #pragma unroll
        for (int j = 0; j < 16; ++j)
          v[j] = __hip_atomic_load(&src[j * 256 + tid],
                                   __ATOMIC_RELAXED, __HIP_MEMORY_SCOPE_AGENT);
        int nready = 0;
        #pragma unroll
        for (int j = 0; j < 16; ++j) {
          if (v[j] != SENT) {
            int off = (((tid >> 1) ^ (j & 7)) << 3) + ((tid & 1) << 2);
            *(uint2*)&hbuf[j * 1024 + off] = *(uint2*)&v[j];
            ++nready;
          }
        }
        if (nready == 16) break;
        __builtin_amdgcn_s_sleep(1);
      }
    }
    __syncthreads();   // S2: hbuf fully deposited
  }
}

// ---------------- logits GEMM: 256x256, one-barrier dbuf, 1024 threads (16 waves, 4/SIMD) ----------------
// Same validated structure as round 14/16; 2x waves per SIMD to hide the vmcnt drain.
__global__ __launch_bounds__(1024, 1) void k_gemm(
    const __hip_bfloat16* __restrict__ H,    // [3200][1024] (rows 3168..3199 zero)
    const __hip_bfloat16* __restrict__ WT,   // [32000][1024]
    const float* __restrict__ b_lm,
    float* __restrict__ out) {
  extern __shared__ char glds[];
  __hip_bfloat16* As = (__hip_bfloat16*)glds;            // [2][256*64] = 64 KB
  __hip_bfloat16* Bs = (__hip_bfloat16*)(glds + 65536);  // [2][256*64] = 64 KB

  // XCD-bijective remap: nwg = 1625 = 8*203 + 1
  int bid = blockIdx.x;
  int xcd = bid & 7;
  int idx = bid >> 3;
  int wg = (xcd < 1 ? xcd * 204 : 204 + (xcd - 1) * 203) + idx;
  // GM=13 raster: all 13 m-tiles consecutive per B panel (nt), mt fastest
  int nt = wg / 13;            // 0..124
  int mt = wg - nt * 13;       // 0..12
  const int mbase = mt * 256;
  const int nbase = nt * 256;

  const int tid = threadIdx.x;
  const int lane = tid & 63;
  const int wid = tid >> 6;      // 0..15
  const int wm = wid >> 2;       // 0..3  (M 64-band)
  const int wn = wid & 3;        // 0..3  (N 64-band)

  f32x4 acc[4][4];
  #pragma unroll
  for (int m = 0; m < 4; ++m)
    #pragma unroll
    for (int n = 0; n < 4; ++n) acc[m][n] = (f32x4){0.f, 0.f, 0.f, 0.f};

  const int kg = lane >> 4;

  int srowA[2], srowB[2], soff[2];
  #pragma unroll
  for (int j = 0; j < 2; ++j) {
    int c = j * 1024 + tid;
    int row = c >> 3;
    srowB[j] = nbase + row;
    srowA[j] = min(mbase + row, MPAD - 1);   // clamp pad rows (zeros)
    soff[j] = ((c & 7) ^ (row & 7)) * 8;
  }
  const int ldsbase = (tid & 960) * 8;       // wave-uniform: wid*512 elems

  auto STAGE = [&](int nb, int kt) {
    #pragma unroll
    for (int j = 0; j < 2; ++j)
      gload_lds16(H + (size_t)srowA[j] * 1024 + kt * 64 + soff[j],
                  As + nb * 16384 + j * 8192 + ldsbase);
    #pragma unroll
    for (int j = 0; j < 2; ++j)
      gload_lds16(WT + (size_t)srowB[j] * 1024 + kt * 64 + soff[j],
                  Bs + nb * 16384 + j * 8192 + ldsbase);
  };
  auto COMPUTE = [&](int nb) {
    __builtin_amdgcn_s_setprio(1);
    #pragma unroll
    for (int kk = 0; kk < 2; ++kk) {
      const int slot = kk * 4 + kg;
      short8 a[4], b[4];
      #pragma unroll
      for (int m = 0; m < 4; ++m) {
        int r = wm * 64 + m * 16 + (lane & 15);
        a[m] = *(const short8*)&As[nb * 16384 + r * 64 + ((slot ^ (r & 7)) << 3)];
      }
      #pragma unroll
      for (int n = 0; n < 4; ++n) {
        int r = wn * 64 + n * 16 + (lane & 15);
        b[n] = *(const short8*)&Bs[nb * 16384 + r * 64 + ((slot ^ (r & 7)) << 3)];
      }
      #pragma unroll
      for (int m = 0; m < 4; ++m)
        #pragma unroll
        for (int n = 0; n < 4; ++n)
          acc[m][n] = __builtin_amdgcn_mfma_f32_16x16x32_bf16(a[m], b[n], acc[m][n], 0, 0, 0);
    }
    __builtin_amdgcn_s_setprio(0);
  };

  STAGE(0, 0);
  asm volatile("s_waitcnt vmcnt(0)" ::: "memory");
  __builtin_amdgcn_s_barrier();
  for (int kt = 0; kt < 16; ++kt) {
    if (kt < 15) STAGE((kt + 1) & 1, kt + 1);
    COMPUTE(kt & 1);
    asm volatile("s_waitcnt vmcnt(0)" ::: "memory");
    __builtin_amdgcn_s_barrier();
  }

  if (mt != 12) {
    #pragma unroll
    for (int n = 0; n < 4; ++n) {
      int gcol = nbase + wn * 64 + n * 16 + (lane & 15);
      float bl = b_lm[gcol];
      #pragma unroll
      for (int m = 0; m < 4; ++m) {
        int rbase = mbase + wm * 64 + m * 16 + ((lane >> 4) << 2);
        #pragma unroll
        for (int q = 0; q < 4; ++q)
          __builtin_nontemporal_store(acc[m][n][q] + bl,
              &out[(size_t)(rbase + q + 32) * V_ + gcol]);
      }
    }
  } else {
    #pragma unroll
    for (int n = 0; n < 4; ++n) {
      int gcol = nbase + wn * 64 + n * 16 + (lane & 15);
      float bl = b_lm[gcol];
      #pragma unroll
      for (int m = 0; m < 4; ++m) {
        int rbase = mbase + wm * 64 + m * 16 + ((lane >> 4) << 2);
        #pragma unroll
        for (int q = 0; q < 4; ++q) {
          int r = rbase + q;
          if (r < MROWS)
            __builtin_nontemporal_store(acc[m][n][q] + bl,
                &out[(size_t)(r + 32) * V_ + gcol]);
        }
      }
    }
  }
}

extern "C" void kernel_launch(void* const* d_in, const int* in_sizes, int n_in,
                              void* d_out, int out_size, void* d_ws, size_t ws_size,
                              hipStream_t stream) {
  const float* features = (const float*)d_in[0];
  // d_in[1]=W_fk, d_in[2]=b_fk, d_in[5]=W_tk, d_in[6]=b_tk : dead code (softmax over size-1 axis)
  const float* W_fv = (const float*)d_in[3];
  const float* b_fv = (const float*)d_in[4];
  const float* W_ih = (const float*)d_in[7];
  const float* W_hh = (const float*)d_in[8];
  const float* b_ih = (const float*)d_in[9];
  const float* b_hh = (const float*)d_in[10];
  const float* W_lm = (const float*)d_in[11];
  const float* b_lm = (const float*)d_in[12];
  const float* bos  = (const float*)d_in[13];
  float* out = (float*)d_out;
  char* ws = (char*)d_ws;

  __hip_bfloat16* WT     = (__hip_bfloat16*)(ws + OFF_WT);
  __hip_bfloat16* H      = (__hip_bfloat16*)(ws + OFF_H);
  unsigned long long* Hq = (unsigned long long*)(ws + OFF_H);
  float* fsum            = (float*)(ws + OFF_FSUM);
  float* ctxp            = (float*)(ws + OFF_CTXP);
  float* gbasep          = (float*)(ws + OFF_GBASEP);

  hipLaunchKernelGGL(k_fsum,  dim3(384),       dim3(256), 0, stream, features, fsum, Hq);
  hipLaunchKernelGGL(k_ctx,   dim3(16, 2, 2),  dim3(256), 0, stream, fsum, W_fv, b_fv, ctxp);
  hipLaunchKernelGGL(k_gbase, dim3(16, 2, 4),  dim3(256), 0, stream, ctxp, W_ih, b_ih, b_hh, gbasep);
  // blocks 0..127: recurrence; 128..255: one-hot + pad zero + W_lm->WT (concurrent, NT)
  hipLaunchKernelGGL(k_rec,   dim3(256),  dim3(256), 163840, stream,
                     gbasep, W_hh, bos, Hq, W_lm, WT, out);
  hipLaunchKernelGGL(k_gemm,  dim3(1625), dim3(1024), 131072, stream, H, WT, b_lm, out);
}

// Round 18
// 686.421 us; speedup vs baseline: 1.1462x; 1.0913x over previous
//
#include <hip/hip_runtime.h>
#include <hip/hip_bf16.h>
#include <stdint.h>

typedef __attribute__((ext_vector_type(8))) short short8;
typedef __attribute__((ext_vector_type(4))) float f32x4;

#define B_ 32
#define N_ 196
#define D_ 1024
#define V_ 32000
#define NSTEP 99
#define MROWS 3168   // 99*32
#define MPAD  3200
#define SENT  0x7FC07FC07FC07FC0ULL   // 4x bf16 NaN: unreachable as packed h (|h|<1)

// workspace layout (bytes)
#define OFF_WT     0ULL          // bf16 [32000][1024]  = 65,536,000
#define OFF_H      65536000ULL   // bf16 [3200][1024]   =  6,553,600  (u64 view: [99][8192] + pad)
#define OFF_FSUM   72089600ULL   // f32  [32][1024]
#define OFF_CTXP   72220672ULL   // f32  [2][32][1024]  partials
#define OFF_GBASEP 72482816ULL   // f32  [4][32][4096]  partials

#define AS3 __attribute__((address_space(3)))
#define AS1 __attribute__((address_space(1)))
static __device__ __forceinline__ void gload_lds16(const void* g, void* l) {
  __builtin_amdgcn_global_load_lds((const AS1 uint32_t*)g, (AS3 uint32_t*)l, 16, 0, 0);
}

// ---------------- fsum (blocks 0..127) + sentinel-fill H (blocks 128..383) ----------------
__global__ void k_fsum(const float* __restrict__ feat, float* __restrict__ fsum,
                       unsigned long long* __restrict__ Hq) {
  if (blockIdx.x >= 128) {
    int gid = (blockIdx.x - 128) * 256 + threadIdx.x;   // 65536 threads
    for (int w = gid; w < NSTEP * 8192; w += 65536) Hq[w] = SENT;
    return;
  }
  int idx = blockIdx.x * 256 + threadIdx.x;           // 32768
  int b = idx >> 10, e = idx & 1023;
  const float* p = feat + (size_t)b * (N_ * D_) + e;
  float s = 0.f;
  #pragma unroll 4
  for (int n = 0; n < N_; ++n) s += fmaxf(p[(size_t)n * D_], 0.f);
  fsum[idx] = s;
}

// ---------------- ctxp[kc] = fsum[:,e-chunk] @ W_fv[e-chunk,:] (+196*b_fv in kc0) ----------------
__global__ void k_ctx(const float* __restrict__ fsum, const float* __restrict__ W_fv,
                      const float* __restrict__ b_fv, float* __restrict__ ctxp) {
  __shared__ float fs[16][512];                       // 32 KB
  int kc = blockIdx.z;                                // e-chunk 0..1
  int e0 = kc * 512;
  int b0 = blockIdx.y * 16;
  int d = blockIdx.x * 64 + (threadIdx.x & 63);
  int bq = threadIdx.x >> 6;                          // 4 batch-quads
  for (int i = threadIdx.x; i < 8192; i += 256)
    fs[i >> 9][i & 511] = fsum[(b0 + (i >> 9)) * 1024 + e0 + (i & 511)];
  __syncthreads();
  float bias = (kc == 0) ? 196.f * b_fv[d] : 0.f;
  float acc[4] = {bias, bias, bias, bias};
  for (int e4 = 0; e4 < 128; ++e4) {
    float w0 = W_fv[(size_t)(e0 + 4 * e4 + 0) * 1024 + d];
    float w1 = W_fv[(size_t)(e0 + 4 * e4 + 1) * 1024 + d];
    float w2 = W_fv[(size_t)(e0 + 4 * e4 + 2) * 1024 + d];
    float w3 = W_fv[(size_t)(e0 + 4 * e4 + 3) * 1024 + d];
    #pragma unroll
    for (int r = 0; r < 4; ++r) {
      float4 c = *(const float4*)&fs[bq * 4 + r][e4 * 4];
      acc[r] = fmaf(c.x, w0, fmaf(c.y, w1, fmaf(c.z, w2, fmaf(c.w, w3, acc[r]))));
    }
  }
  #pragma unroll
  for (int r = 0; r < 4; ++r)
    ctxp[kc * 32768 + (size_t)(b0 + bq * 4 + r) * 1024 + d] = acc[r];
}

// ---------------- gbasep[kc] = ctx[:,e-chunk] @ W_ih[e-chunk,:] (+biases in kc0) ----------------
__global__ void k_gbase(const float* __restrict__ ctxp, const float* __restrict__ W_ih,
                        const float* __restrict__ b_ih, const float* __restrict__ b_hh,
                        float* __restrict__ gbasep) {
  __shared__ float cs[16][256];                       // 16 KB
  int kc = blockIdx.z;                                // e-chunk 0..3
  int e0 = kc * 256;
  int b0 = blockIdx.y * 16;
  int j = blockIdx.x * 256 + threadIdx.x;
  for (int i = threadIdx.x; i < 4096; i += 256) {
    int r = i >> 8, e = i & 255;
    cs[r][e] = ctxp[(size_t)(b0 + r) * 1024 + e0 + e]
             + ctxp[32768 + (size_t)(b0 + r) * 1024 + e0 + e];
  }
  __syncthreads();
  float bias = (kc == 0) ? (b_ih[j] + b_hh[j]) : 0.f;
  float acc[16];
  #pragma unroll
  for (int r = 0; r < 16; ++r) acc[r] = bias;
  for (int e4 = 0; e4 < 64; ++e4) {
    float w0 = W_ih[(size_t)(e0 + 4 * e4 + 0) * 4096 + j];
    float w1 = W_ih[(size_t)(e0 + 4 * e4 + 1) * 4096 + j];
    float w2 = W_ih[(size_t)(e0 + 4 * e4 + 2) * 4096 + j];
    float w3 = W_ih[(size_t)(e0 + 4 * e4 + 3) * 4096 + j];
    #pragma unroll
    for (int r = 0; r < 16; ++r) {
      float4 c = *(const float4*)&cs[r][e4 * 4];
      acc[r] = fmaf(c.x, w0, fmaf(c.y, w1, fmaf(c.z, w2, fmaf(c.w, w3, acc[r]))));
    }
  }
  #pragma unroll
  for (int r = 0; r < 16; ++r)
    gbasep[kc * 131072 + (size_t)(b0 + r) * 4096 + j] = acc[r];
}

// ---------------- persistent LSTM recurrence (blocks 0..127) + workers (128..255) ----------------
// 4x32 decomposition: block (bq,dg) owns 8 batches x 32 dims (128 gate cols), 512 threads,
// 8 waves x 1 MFMA col-tile, breg via K-half staging rounds (compile-time indices).
// Poll = 8 batch rows = 16 KB/step, 4 words/thread. Workers: round-15 512-thread code.
__global__ __launch_bounds__(512, 1) void k_rec(
    const float* __restrict__ gbasep, const float* __restrict__ W_hh,
    const float* __restrict__ bos, unsigned long long* __restrict__ Hq,
    const float* __restrict__ W_lm, __hip_bfloat16* __restrict__ WT,
    float* __restrict__ out) {
  extern __shared__ char lds[];
  const int tid = threadIdx.x;
  const int blk = blockIdx.x;
  const int lane = tid & 63;
  const int wid = tid >> 6;        // 0..7

  if (blk >= 128) {
    // ---------- worker blocks (512 threads) ----------
    __hip_bfloat16* t = (__hip_bfloat16*)lds;          // [64][66]
    int wblk = blk - 128;
    for (int idx = wblk * 512 + tid; idx < B_ * V_; idx += 128 * 512)
      __builtin_nontemporal_store(((idx % V_) == 0) ? 1.0f : 0.0f, &out[idx]);
    // zero TRUE pad rows 3168..3199 (32 rows x 256 u64)
    if (wblk < 16) Hq[(size_t)MROWS * 256 + wblk * 512 + tid] = 0ULL;
    int tx = tid & 63, ty = tid >> 6;                  // 8 waves
    int word = tx & 31, nh = tx >> 5;
    for (int tile = wblk; tile < 8000; tile += 128) {
      int k0 = (tile & 15) * 64;
      int n0 = (tile >> 4) * 64;
      __syncthreads();
      #pragma unroll
      for (int i = 0; i < 8; ++i) {
        int r = i * 8 + ty;
        t[r * 66 + tx] = __float2bfloat16(
            __builtin_nontemporal_load(&W_lm[(size_t)(k0 + r) * V_ + n0 + tx]));
      }
      __syncthreads();
      #pragma unroll
      for (int i = 0; i < 4; ++i) {
        int n = i * 16 + ty * 2 + nh;
        uint32_t lo = *(const uint16_t*)&t[2 * word * 66 + n];
        uint32_t hi = *(const uint16_t*)&t[(2 * word + 1) * 66 + n];
        __builtin_nontemporal_store(lo | (hi << 16),
            (uint32_t*)&WT[(size_t)(n0 + n) * 1024 + k0] + word);
      }
    }
    return;
  }

  // ---------- recurrence blocks ----------
  __hip_bfloat16* hbuf = (__hip_bfloat16*)lds;             // [16][1024] (rows 8..15 zero) 32 KB
  __hip_bfloat16* wbuf = (__hip_bfloat16*)(lds + 32768);   // [128 cols][512 K] per round, 128 KB
  float* gexb = (float*)(lds + 32768);                     // [2][16][132] f32, aliases wbuf

  const int bq = blk >> 5;     // batch quarter 0..3 (batches bq*8..+8)
  const int dg = blk & 31;     // dim group 0..31 (dims dg*32..+32)

  // h0: rows 0..7 = bos, rows 8..15 = 0 (MFMA pad rows)
  for (int idx = tid; idx < 16 * 1024; idx += 512) {
    int row = idx >> 10;
    int k = idx & 1023;
    float v = (row < 8) ? bos[k] : 0.f;
    hbuf[row * 1024 + ((((k >> 3) ^ (row & 7)) << 3) | (k & 7))] = __float2bfloat16(v);
  }

  const int arow = lane & 15;          // batch row (rows 8..15 compute discarded zeros)
  const int bcol = wid * 16 + (lane & 15);   // local col 0..127 (col = gate*32 + dim32)
  const int kg = lane >> 4;
  const int axor = arow & 7;

  // W_hh slice -> breg[32] via two K-half staging rounds (no conditional writes,
  // all breg indices compile-time)
  short8 breg[32];
#define WROUND(R)                                                                   \
  __syncthreads();                                                                  \
  for (int idx = tid; idx < 65536; idx += 512) {                                    \
    int c = idx & 127;                                                              \
    int kk = idx >> 7;                                                              \
    float w = W_hh[(size_t)((R) * 512 + kk) * 4096 + (c >> 5) * 1024 + dg * 32 + (c & 31)]; \
    wbuf[c * 512 + ((((kk >> 3) ^ (c & 7)) << 3) | (kk & 7))] = __float2bfloat16(w); \
  }                                                                                 \
  __syncthreads();                                                                  \
  _Pragma("unroll")                                                                 \
  for (int j = 0; j < 16; ++j) {                                                    \
    int ck = j * 4 + kg;                                                            \
    breg[(R) * 16 + j] = *(const short8*)&wbuf[bcol * 512 + ((ck ^ (bcol & 7)) << 3)]; \
  }
  WROUND(0)
  WROUND(1)
#undef WROUND

  const int btl = tid >> 5;    // local batch 0..7 (valid tid<256)
  const int dl = tid & 31;     // local dim 0..31
  float gb0 = 0.f, gb1 = 0.f, gb2 = 0.f, gb3 = 0.f;
  if (tid < 256) {
    #pragma unroll
    for (int kc = 0; kc < 4; ++kc) {
      size_t base = (size_t)kc * 131072 + (size_t)(bq * 8 + btl) * 4096 + dg * 32 + dl;
      gb0 += gbasep[base + 0 * 1024];
      gb1 += gbasep[base + 1 * 1024];
      gb2 += gbasep[base + 2 * 1024];
      gb3 += gbasep[base + 3 * 1024];
    }
  }
  float cst = 0.f;

  const int pubw = (bq * 8 + (btl & 7)) * 256 + dg * 8 + (dl >> 2);

  __syncthreads();   // extraction done -> gex (aliases wbuf) safe to write

  for (int t = 0; t < NSTEP; ++t) {
    float* gex = gexb + (t & 1) * (16 * 132);   // parity buffer
    f32x4 acc0 = {0.f, 0.f, 0.f, 0.f};
    f32x4 acc1 = {0.f, 0.f, 0.f, 0.f};
    #pragma unroll
    for (int kt = 0; kt < 32; kt += 2) {
      int ca = kt * 4 + kg;
      short8 a0 = *(const short8*)&hbuf[arow * 1024 + ((ca ^ axor) << 3)];
      acc0 = __builtin_amdgcn_mfma_f32_16x16x32_bf16(a0, breg[kt], acc0, 0, 0, 0);
      short8 a1 = *(const short8*)&hbuf[arow * 1024 + (((ca + 4) ^ axor) << 3)];
      acc1 = __builtin_amdgcn_mfma_f32_16x16x32_bf16(a1, breg[kt + 1], acc1, 0, 0, 0);
    }
    acc0 = acc0 + acc1;
    {
      int brow = (lane >> 4) << 2;
      #pragma unroll
      for (int q = 0; q < 4; ++q) gex[(brow + q) * 132 + bcol] = acc0[q];
    }
    __syncthreads();   // S1: gex[t&1] written by all 8 waves

    if (tid < 256) {
      float gi = gex[btl * 132 + 0  + dl] + gb0;
      float gf = gex[btl * 132 + 32 + dl] + gb1;
      float gg = gex[btl * 132 + 64 + dl] + gb2;
      float go = gex[btl * 132 + 96 + dl] + gb3;
      float si = 1.f / (1.f + __expf(-gi));
      float sf = 1.f / (1.f + __expf(-gf));
      float so = 1.f / (1.f + __expf(-go));
      cst = sf * cst + si * tanhf(gg);
      float h = so * tanhf(cst);

      float h1 = __shfl_down(h, 1);
      float h2 = __shfl_down(h, 2);
      float h3 = __shfl_down(h, 3);
      if ((dl & 3) == 0) {
        __hip_bfloat16 q0 = __float2bfloat16(h), q1 = __float2bfloat16(h1);
        __hip_bfloat16 q2 = __float2bfloat16(h2), q3 = __float2bfloat16(h3);
        unsigned long long v = (unsigned long long)*(uint16_t*)&q0
                             | ((unsigned long long)*(uint16_t*)&q1 << 16)
                             | ((unsigned long long)*(uint16_t*)&q2 << 32)
                             | ((unsigned long long)*(uint16_t*)&q3 << 48);
        __hip_atomic_store(&Hq[(size_t)t * 8192 + pubw], v,
                           __ATOMIC_RELAXED, __HIP_MEMORY_SCOPE_AGENT);
      }
    }

    if (t == NSTEP - 1) break;

    // poll own 8 batch rows of H[t]: 4 words/thread, unconditional batched loads
    {
      const unsigned long long* src = Hq + (size_t)t * 8192 + (size_t)bq * 8 * 256;
      for (;;) {
        unsigned long long v[4];
        #pragma unroll
        for (int j = 0; j < 4; ++j)
          v[j] = __hip_atomic_load(&src[j * 512 + tid],
                                   __ATOMIC_RELAXED, __HIP_MEMORY_SCOPE_AGENT);
        int nready = 0;
        #pragma unroll
        for (int j = 0; j < 4; ++j) {
          if (v[j] != SENT) {
            int w = j * 512 + tid;
            int row = w >> 8, c = w & 255;
            int off = (((c >> 1) ^ (row & 7)) << 3) + ((c & 1) << 2);
            *(uint2*)&hbuf[row * 1024 + off] = *(uint2*)&v[j];
            ++nready;
          }
        }
        if (nready == 4) break;
        __builtin_amdgcn_s_sleep(1);
      }
    }
    __syncthreads();   // S2: hbuf fully deposited
  }
}

// ---------------- logits GEMM: 256x256, one-barrier dbuf, 1024 threads (round-17 best) ----------------
__global__ __launch_bounds__(1024, 1) void k_gemm(
    const __hip_bfloat16* __restrict__ H,    // [3200][1024] (rows 3168..3199 zero)
    const __hip_bfloat16* __restrict__ WT,   // [32000][1024]
    const float* __restrict__ b_lm,
    float* __restrict__ out) {
  extern __shared__ char glds[];
  __hip_bfloat16* As = (__hip_bfloat16*)glds;            // [2][256*64] = 64 KB
  __hip_bfloat16* Bs = (__hip_bfloat16*)(glds + 65536);  // [2][256*64] = 64 KB

  // XCD-bijective remap: nwg = 1625 = 8*203 + 1
  int bid = blockIdx.x;
  int xcd = bid & 7;
  int idx = bid >> 3;
  int wg = (xcd < 1 ? xcd * 204 : 204 + (xcd - 1) * 203) + idx;
  // GM=13 raster: all 13 m-tiles consecutive per B panel (nt), mt fastest
  int nt = wg / 13;            // 0..124
  int mt = wg - nt * 13;       // 0..12
  const int mbase = mt * 256;
  const int nbase = nt * 256;

  const int tid = threadIdx.x;
  const int lane = tid & 63;
  const int wid = tid >> 6;      // 0..15
  const int wm = wid >> 2;       // 0..3  (M 64-band)
  const int wn = wid & 3;        // 0..3  (N 64-band)

  f32x4 acc[4][4];
  #pragma unroll
  for (int m = 0; m < 4; ++m)
    #pragma unroll
    for (int n = 0; n < 4; ++n) acc[m][n] = (f32x4){0.f, 0.f, 0.f, 0.f};

  const int kg = lane >> 4;

  int srowA[2], srowB[2], soff[2];
  #pragma unroll
  for (int j = 0; j < 2; ++j) {
    int c = j * 1024 + tid;
    int row = c >> 3;
    srowB[j] = nbase + row;
    srowA[j] = min(mbase + row, MPAD - 1);   // clamp pad rows (zeros)
    soff[j] = ((c & 7) ^ (row & 7)) * 8;
  }
  const int ldsbase = (tid & 960) * 8;       // wave-uniform: wid*512 elems

  auto STAGE = [&](int nb, int kt) {
    #pragma unroll
    for (int j = 0; j < 2; ++j)
      gload_lds16(H + (size_t)srowA[j] * 1024 + kt * 64 + soff[j],
                  As + nb * 16384 + j * 8192 + ldsbase);
    #pragma unroll
    for (int j = 0; j < 2; ++j)
      gload_lds16(WT + (size_t)srowB[j] * 1024 + kt * 64 + soff[j],
                  Bs + nb * 16384 + j * 8192 + ldsbase);
  };
  auto COMPUTE = [&](int nb) {
    __builtin_amdgcn_s_setprio(1);
    #pragma unroll
    for (int kk = 0; kk < 2; ++kk) {
      const int slot = kk * 4 + kg;
      short8 a[4], b[4];
      #pragma unroll
      for (int m = 0; m < 4; ++m) {
        int r = wm * 64 + m * 16 + (lane & 15);
        a[m] = *(const short8*)&As[nb * 16384 + r * 64 + ((slot ^ (r & 7)) << 3)];
      }
      #pragma unroll
      for (int n = 0; n < 4; ++n) {
        int r = wn * 64 + n * 16 + (lane & 15);
        b[n] = *(const short8*)&Bs[nb * 16384 + r * 64 + ((slot ^ (r & 7)) << 3)];
      }
      #pragma unroll
      for (int m = 0; m < 4; ++m)
        #pragma unroll
        for (int n = 0; n < 4; ++n)
          acc[m][n] = __builtin_amdgcn_mfma_f32_16x16x32_bf16(a[m], b[n], acc[m][n], 0, 0, 0);
    }
    __builtin_amdgcn_s_setprio(0);
  };

  STAGE(0, 0);
  asm volatile("s_waitcnt vmcnt(0)" ::: "memory");
  __builtin_amdgcn_s_barrier();
  for (int kt = 0; kt < 16; ++kt) {
    if (kt < 15) STAGE((kt + 1) & 1, kt + 1);
    COMPUTE(kt & 1);
    asm volatile("s_waitcnt vmcnt(0)" ::: "memory");
    __builtin_amdgcn_s_barrier();
  }

  if (mt != 12) {
    #pragma unroll
    for (int n = 0; n < 4; ++n) {
      int gcol = nbase + wn * 64 + n * 16 + (lane & 15);
      float bl = b_lm[gcol];
      #pragma unroll
      for (int m = 0; m < 4; ++m) {
        int rbase = mbase + wm * 64 + m * 16 + ((lane >> 4) << 2);
        #pragma unroll
        for (int q = 0; q < 4; ++q)
          __builtin_nontemporal_store(acc[m][n][q] + bl,
              &out[(size_t)(rbase + q + 32) * V_ + gcol]);
      }
    }
  } else {
    #pragma unroll
    for (int n = 0; n < 4; ++n) {
      int gcol = nbase + wn * 64 + n * 16 + (lane & 15);
      float bl = b_lm[gcol];
      #pragma unroll
      for (int m = 0; m < 4; ++m) {
        int rbase = mbase + wm * 64 + m * 16 + ((lane >> 4) << 2);
        #pragma unroll
        for (int q = 0; q < 4; ++q) {
          int r = rbase + q;
          if (r < MROWS)
            __builtin_nontemporal_store(acc[m][n][q] + bl,
                &out[(size_t)(r + 32) * V_ + gcol]);
        }
      }
    }
  }
}

extern "C" void kernel_launch(void* const* d_in, const int* in_sizes, int n_in,
                              void* d_out, int out_size, void* d_ws, size_t ws_size,
                              hipStream_t stream) {
  const float* features = (const float*)d_in[0];
  // d_in[1]=W_fk, d_in[2]=b_fk, d_in[5]=W_tk, d_in[6]=b_tk : dead code (softmax over size-1 axis)
  const float* W_fv = (const float*)d_in[3];
  const float* b_fv = (const float*)d_in[4];
  const float* W_ih = (const float*)d_in[7];
  const float* W_hh = (const float*)d_in[8];
  const float* b_ih = (const float*)d_in[9];
  const float* b_hh = (const float*)d_in[10];
  const float* W_lm = (const float*)d_in[11];
  const float* b_lm = (const float*)d_in[12];
  const float* bos  = (const float*)d_in[13];
  float* out = (float*)d_out;
  char* ws = (char*)d_ws;

  __hip_bfloat16* WT     = (__hip_bfloat16*)(ws + OFF_WT);
  __hip_bfloat16* H      = (__hip_bfloat16*)(ws + OFF_H);
  unsigned long long* Hq = (unsigned long long*)(ws + OFF_H);
  float* fsum            = (float*)(ws + OFF_FSUM);
  float* ctxp            = (float*)(ws + OFF_CTXP);
  float* gbasep          = (float*)(ws + OFF_GBASEP);

  hipLaunchKernelGGL(k_fsum,  dim3(384),       dim3(256), 0, stream, features, fsum, Hq);
  hipLaunchKernelGGL(k_ctx,   dim3(16, 2, 2),  dim3(256), 0, stream, fsum, W_fv, b_fv, ctxp);
  hipLaunchKernelGGL(k_gbase, dim3(16, 2, 4),  dim3(256), 0, stream, ctxp, W_ih, b_ih, b_hh, gbasep);
  // blocks 0..127: recurrence (4x32 decomp); 128..255: one-hot + pad zero + convT (NT)
  hipLaunchKernelGGL(k_rec,   dim3(256),  dim3(512), 163840, stream,
                     gbasep, W_hh, bos, Hq, W_lm, WT, out);
  hipLaunchKernelGGL(k_gemm,  dim3(1625), dim3(1024), 131072, stream, H, WT, b_lm, out);
}